// Round 9
// baseline (1414.220 us; speedup 1.0000x reference)
//
#include <hip/hip_runtime.h>
#include <math.h>

#define N_NODES 20000
#define N_EDGES 320000
#define D_IN    3072

#define M_PAD   20096   // 157 * 128
#define N1_PAD  1024
#define LDH1    1024
#define K2_PAD  1024
#define N2_PAD  384
#define LDH2    384

typedef short bf16x8 __attribute__((ext_vector_type(8)));
typedef float f32x4  __attribute__((ext_vector_type(4)));

#define GLOAD_LDS16(g, l) __builtin_amdgcn_global_load_lds( \
    (const __attribute__((address_space(1))) void*)(g),     \
    (__attribute__((address_space(3))) void*)(l), 16, 0, 0)

__device__ inline unsigned short f2bf(float x) {
    union { float f; unsigned u; } v; v.f = x;
    unsigned r = (v.u + 0x7FFFu + ((v.u >> 16) & 1u)) >> 16;
    return (unsigned short)r;
}
__device__ inline float bf2f(unsigned short h) {
    union { float f; unsigned u; } v; v.u = ((unsigned)h) << 16;
    return v.f;
}

// ---------------- CSR build ----------------

__global__ void zero_counts_kernel(int* __restrict__ counts) {
    int i = blockIdx.x * blockDim.x + threadIdx.x;
    if (i < N_NODES) counts[i] = 0;
}

__global__ void count_kernel(const int* __restrict__ dst, int* __restrict__ counts) {
    int e = blockIdx.x * blockDim.x + threadIdx.x;
    if (e < N_EDGES) atomicAdd(&counts[dst[e]], 1);
}

__global__ void scan_kernel(const int* __restrict__ counts, int* __restrict__ row_start,
                            int* __restrict__ cursor) {
    __shared__ int part[1024];
    const int T = 1024;
    int t = threadIdx.x;
    const int chunk = (N_NODES + T - 1) / T;
    int lo = t * chunk;
    int hi = lo + chunk; if (hi > N_NODES) hi = N_NODES;
    int s = 0;
    for (int i = lo; i < hi; ++i) s += counts[i];
    part[t] = s;
    __syncthreads();
    for (int off = 1; off < T; off <<= 1) {
        int v = (t >= off) ? part[t - off] : 0;
        __syncthreads();
        part[t] += v;
        __syncthreads();
    }
    int run = part[t] - s;
    for (int i = lo; i < hi; ++i) {
        row_start[i] = run;
        cursor[i] = run;
        run += counts[i];
    }
    if (t == T - 1) row_start[N_NODES] = run;
}

__global__ void scatter_kernel(const int* __restrict__ src, const int* __restrict__ dst,
                               int* __restrict__ cursor, int* __restrict__ esrc) {
    int e = blockIdx.x * blockDim.x + threadIdx.x;
    if (e < N_EDGES) {
        int pos = atomicAdd(&cursor[dst[e]], 1);
        esrc[pos] = src[e];
    }
}

// ---------------- conversions ----------------

__global__ __launch_bounds__(256)
void convA_kernel(const float* __restrict__ X, unsigned short* __restrict__ Ahi,
                  unsigned short* __restrict__ Alo) {
    int i = blockIdx.x * blockDim.x + threadIdx.x;
    const int total = N_NODES * D_IN / 4;
    if (i >= total) return;
    float4 v = reinterpret_cast<const float4*>(X)[i];
    unsigned short h0 = f2bf(v.x), h1 = f2bf(v.y), h2 = f2bf(v.z), h3 = f2bf(v.w);
    unsigned short l0 = f2bf(v.x - bf2f(h0));
    unsigned short l1 = f2bf(v.y - bf2f(h1));
    unsigned short l2 = f2bf(v.z - bf2f(h2));
    unsigned short l3 = f2bf(v.w - bf2f(h3));
    reinterpret_cast<ushort4*>(Ahi)[i] = make_ushort4(h0, h1, h2, h3);
    reinterpret_cast<ushort4*>(Alo)[i] = make_ushort4(l0, l1, l2, l3);
}

__global__ __launch_bounds__(256)
void convW_kernel(const float* __restrict__ W, unsigned short* __restrict__ WhiT,
                  unsigned short* __restrict__ WloT, int K, int N, int K_PAD) {
    __shared__ float sh[32][33];
    const int t  = threadIdx.x;
    const int tx = t & 31;
    const int ty = t >> 5;
    const int n0 = blockIdx.x * 32;
    const int k0 = blockIdx.y * 32;
    #pragma unroll
    for (int it = 0; it < 4; ++it) {
        int k = k0 + ty + it * 8;
        int n = n0 + tx;
        sh[ty + it * 8][tx] = (k < K && n < N) ? W[(long)k * N + n] : 0.f;
    }
    __syncthreads();
    #pragma unroll
    for (int it = 0; it < 4; ++it) {
        int n = n0 + ty + it * 8;
        int k = k0 + tx;
        float v = sh[tx][ty + it * 8];
        unsigned short h = f2bf(v);
        unsigned short l = f2bf(v - bf2f(h));
        WhiT[(long)n * K_PAD + k] = h;
        WloT[(long)n * K_PAD + k] = l;
    }
}

// ---------------- split-bf16 MFMA GEMM, 3-phase single-buffer (r7) + parity-fixed swizzle ----------------
// H = Ahi*Bhi + Ahi*Blo + Alo*Bhi + bias.
// r9 change: swizzle slot bit-select (r&3) -> ((r>>1)&3). Row stride 64B means a
// row's banks are keyed by r&1 (16*(r&1)); slot index must be INDEPENDENT of r&1
// to spread the 8 same-parity lanes of a quarter-wave across all 4 16B slots:
// (fr&3) correlates with fr&1 (even rows only hit slots {0,2} -> 4-way);
// ((fr>>1)&3) gives 2 lanes/slot = 2-way = free (m136). Since arow+i*16 is a
// multiple of 16, (row>>1)&3 == (fr>>1)&3 — consistent with the staging-side
// pre-swizzle which uses the staged row r0/r1 directly.
// Schedule (verified r7): single 32KB buffer, slot rotation, derived vmcnt gates:
//   p1(t): gate vmcnt(2) [t=0: 4]; read Ahi,Bhi; issue Alo(t) [t>0]
//   p2(t): gate vmcnt(2);          read Blo;     issue Ahi,Bhi(t+1) [t<NT-1]
//   p3(t): gate vmcnt(4) [last:0]; read Alo;     issue Blo(t+1)     [t<NT-1]

#define GBM 128
#define GBN 128
#define GBK 32

#define ISSUE2(p0, p1, ss) do { \
    GLOAD_LDS16(p0, &lds[ss][wid * 1024]); \
    GLOAD_LDS16(p1, &lds[ss][wid * 1024 + 4096]); \
    p0 += GBK; p1 += GBK; } while (0)

__global__ __launch_bounds__(256, 4)
void gemm_split_mfma_kernel(const unsigned short* __restrict__ Ahi,
                            const unsigned short* __restrict__ Alo,
                            const unsigned short* __restrict__ BhiT,
                            const unsigned short* __restrict__ BloT,
                            const float* __restrict__ bias, float* __restrict__ H,
                            int K, int NB, int ldh, int nbias) {
    // slots: 0=Ahi 1=Alo 2=Bhi 3=Blo (8KB each, single copy)
    __shared__ __align__(16) char lds[4][8192];

    const int t    = threadIdx.x;
    const int wid  = t >> 6;
    const int lane = t & 63;
    const int wr   = wid >> 1;
    const int wc   = wid & 1;

    // bijective XCD swizzle
    const int orig = blockIdx.x;
    const int nwg  = gridDim.x;
    const int xcd  = orig & 7, loc = orig >> 3;
    const int q    = nwg >> 3, r = nwg & 7;
    const int wgid = (xcd < r ? xcd * (q + 1) : r * (q + 1) + (xcd - r) * q) + loc;
    const int m0   = (wgid / NB) * GBM;
    const int n0   = (wgid % NB) * GBN;

    f32x4 acc[4][4] = {};

    const int byt0 = wid * 1024 + lane * 16;
    const int byt1 = byt0 + 4096;
    const int r0 = byt0 >> 6, r1 = byt1 >> 6;
    const int cs0 = (byt0 & 63) ^ (((r0 >> 1) & 3) << 4);   // parity-independent slot
    const int cs1 = (byt1 & 63) ^ (((r1 >> 1) & 3) << 4);

    const unsigned short* pAh0 = Ahi  + (size_t)(m0 + r0) * K + (cs0 >> 1);
    const unsigned short* pAh1 = Ahi  + (size_t)(m0 + r1) * K + (cs1 >> 1);
    const unsigned short* pAl0 = Alo  + (size_t)(m0 + r0) * K + (cs0 >> 1);
    const unsigned short* pAl1 = Alo  + (size_t)(m0 + r1) * K + (cs1 >> 1);
    const unsigned short* pBh0 = BhiT + (size_t)(n0 + r0) * K + (cs0 >> 1);
    const unsigned short* pBh1 = BhiT + (size_t)(n0 + r1) * K + (cs1 >> 1);
    const unsigned short* pBl0 = BloT + (size_t)(n0 + r0) * K + (cs0 >> 1);
    const unsigned short* pBl1 = BloT + (size_t)(n0 + r1) * K + (cs1 >> 1);

    const int fr   = lane & 15;
    const int kbs  = ((lane >> 4) << 4) ^ (((fr >> 1) & 3) << 4); // parity-independent
    const int arow = wr * 64;
    const int brow = wc * 64;

    // prologue: tile 0 fully issued (8 instrs/thread), order Ahi,Bhi,Blo,Alo
    ISSUE2(pAh0, pAh1, 0);
    ISSUE2(pBh0, pBh1, 2);
    ISSUE2(pBl0, pBl1, 3);
    ISSUE2(pAl0, pAl1, 1);

    const int NT = K >> 5;
    bf16x8 ahi[4], bhi[4], blo[4], alo[4];

    for (int tt = 0; tt < NT; ++tt) {
        // ---- phase 1: hi*hi ----
        if (tt == 0) asm volatile("s_waitcnt vmcnt(4)" ::: "memory");
        else         asm volatile("s_waitcnt vmcnt(2)" ::: "memory");
        __builtin_amdgcn_s_barrier();
        #pragma unroll
        for (int i = 0; i < 4; ++i)
            ahi[i] = *(const bf16x8*)(&lds[0][(arow + i * 16 + fr) * 64 + kbs]);
        #pragma unroll
        for (int j = 0; j < 4; ++j)
            bhi[j] = *(const bf16x8*)(&lds[2][(brow + j * 16 + fr) * 64 + kbs]);
        if (tt > 0) ISSUE2(pAl0, pAl1, 1);     // Alo(t): last read of Alo(t-1) was p3(t-1)
        __builtin_amdgcn_s_setprio(1);
        #pragma unroll
        for (int i = 0; i < 4; ++i)
            #pragma unroll
            for (int j = 0; j < 4; ++j)
                acc[i][j] = __builtin_amdgcn_mfma_f32_16x16x32_bf16(ahi[i], bhi[j], acc[i][j], 0, 0, 0);
        __builtin_amdgcn_s_setprio(0);
        // ---- phase 2: hi*lo ----
        asm volatile("s_waitcnt vmcnt(2)" ::: "memory");
        __builtin_amdgcn_s_barrier();
        #pragma unroll
        for (int j = 0; j < 4; ++j)
            blo[j] = *(const bf16x8*)(&lds[3][(brow + j * 16 + fr) * 64 + kbs]);
        if (tt < NT - 1) {                     // Ahi/Bhi(t+1): last reads were p1(t)
            ISSUE2(pAh0, pAh1, 0);
            ISSUE2(pBh0, pBh1, 2);
        }
        __builtin_amdgcn_s_setprio(1);
        #pragma unroll
        for (int i = 0; i < 4; ++i)
            #pragma unroll
            for (int j = 0; j < 4; ++j)
                acc[i][j] = __builtin_amdgcn_mfma_f32_16x16x32_bf16(ahi[i], blo[j], acc[i][j], 0, 0, 0);
        __builtin_amdgcn_s_setprio(0);
        // ---- phase 3: lo*hi ----
        if (tt < NT - 1) asm volatile("s_waitcnt vmcnt(4)" ::: "memory");
        else             asm volatile("s_waitcnt vmcnt(0)" ::: "memory");
        __builtin_amdgcn_s_barrier();
        #pragma unroll
        for (int i = 0; i < 4; ++i)
            alo[i] = *(const bf16x8*)(&lds[1][(arow + i * 16 + fr) * 64 + kbs]);
        if (tt < NT - 1) ISSUE2(pBl0, pBl1, 3); // Blo(t+1): last read was p2(t)
        __builtin_amdgcn_s_setprio(1);
        #pragma unroll
        for (int i = 0; i < 4; ++i)
            #pragma unroll
            for (int j = 0; j < 4; ++j)
                acc[i][j] = __builtin_amdgcn_mfma_f32_16x16x32_bf16(alo[i], bhi[j], acc[i][j], 0, 0, 0);
        __builtin_amdgcn_s_setprio(0);
    }

    // epilogue: C layout col = lane&15, row = (lane>>4)*4 + reg
    #pragma unroll
    for (int i = 0; i < 4; ++i) {
        #pragma unroll
        for (int j = 0; j < 4; ++j) {
            int row = m0 + wr * 64 + i * 16 + (lane >> 4) * 4;
            int col = n0 + wc * 64 + j * 16 + (lane & 15);
            float bv = (col < nbias) ? bias[col] : 0.f;
            #pragma unroll
            for (int r2 = 0; r2 < 4; ++r2)
                H[(size_t)(row + r2) * ldh + col] = acc[i][j][r2] + bv;
        }
    }
}

// ---------------- fp32 tiled GEMM (layers 3-4 + fallback) ----------------

#define BM 64
#define BN 64
#define BKT 16
#define TM 4
#define TN 4

__global__ __launch_bounds__(256)
void gemm_bias_kernel(const float* __restrict__ X, const float* __restrict__ W,
                      const float* __restrict__ bias, float* __restrict__ H,
                      int M, int N, int K) {
    __shared__ float As[BKT][BM];
    __shared__ float Bs[BKT][BN];

    const int t  = threadIdx.x;
    const int tx = t & 15;
    const int ty = t >> 4;
    const int m0 = blockIdx.y * BM;
    const int n0 = blockIdx.x * BN;

    float acc[TM][TN] = {};

    const int arow = t >> 2;
    const int ak0  = (t & 3) * 4;
    const int brow = t >> 4;
    const int bn0  = (t & 15) * 4;

    for (int k0 = 0; k0 < K; k0 += BKT) {
        {
            float4 v = make_float4(0.f, 0.f, 0.f, 0.f);
            int gm = m0 + arow;
            int gk = k0 + ak0;
            if (gm < M) {
                if (gk + 3 < K) {
                    v = *reinterpret_cast<const float4*>(&X[(long)gm * K + gk]);
                } else {
                    float tmp[4] = {0.f, 0.f, 0.f, 0.f};
                    for (int i = 0; i < 4; ++i)
                        if (gk + i < K) tmp[i] = X[(long)gm * K + gk + i];
                    v = make_float4(tmp[0], tmp[1], tmp[2], tmp[3]);
                }
            }
            As[ak0 + 0][arow] = v.x;
            As[ak0 + 1][arow] = v.y;
            As[ak0 + 2][arow] = v.z;
            As[ak0 + 3][arow] = v.w;
        }
        {
            float4 v = make_float4(0.f, 0.f, 0.f, 0.f);
            int gk = k0 + brow;
            int gn = n0 + bn0;
            if (gk < K) {
                if (gn + 3 < N) {
                    v = *reinterpret_cast<const float4*>(&W[(long)gk * N + gn]);
                } else {
                    float tmp[4] = {0.f, 0.f, 0.f, 0.f};
                    for (int i = 0; i < 4; ++i)
                        if (gn + i < N) tmp[i] = W[(long)gk * N + gn + i];
                    v = make_float4(tmp[0], tmp[1], tmp[2], tmp[3]);
                }
            }
            *reinterpret_cast<float4*>(&Bs[brow][bn0]) = v;
        }
        __syncthreads();

        #pragma unroll
        for (int kk = 0; kk < BKT; ++kk) {
            float a[TM], b[TN];
            *reinterpret_cast<float4*>(a) = *reinterpret_cast<const float4*>(&As[kk][ty * TM]);
            *reinterpret_cast<float4*>(b) = *reinterpret_cast<const float4*>(&Bs[kk][tx * TN]);
            #pragma unroll
            for (int i = 0; i < TM; ++i)
                #pragma unroll
                for (int j = 0; j < TN; ++j)
                    acc[i][j] += a[i] * b[j];
        }
        __syncthreads();
    }

    #pragma unroll
    for (int i = 0; i < TM; ++i) {
        int gm = m0 + ty * TM + i;
        if (gm >= M) continue;
        #pragma unroll
        for (int j = 0; j < TN; ++j) {
            int gn = n0 + tx * TN + j;
            if (gn < N) H[(long)gm * N + gn] = acc[i][j] + bias[gn];
        }
    }
}

// ---------------- aggregates ----------------

__global__ __launch_bounds__(256)
void aggregate_bf16_kernel(const float* __restrict__ H, const int* __restrict__ row_start,
                           const int* __restrict__ esrc, unsigned short* __restrict__ Xhi,
                           unsigned short* __restrict__ Xlo, int d, int ld_in, int kpad) {
    const int node = blockIdx.x;
    const int f = threadIdx.x * 4;
    if (f >= kpad) return;
    if (f >= d) {
        ushort4 z = make_ushort4(0, 0, 0, 0);
        *reinterpret_cast<ushort4*>(&Xhi[(size_t)node * kpad + f]) = z;
        *reinterpret_cast<ushort4*>(&Xlo[(size_t)node * kpad + f]) = z;
        return;
    }
    const int beg = row_start[node];
    const int end = row_start[node + 1];
    float4 acc = *reinterpret_cast<const float4*>(&H[(size_t)node * ld_in + f]);
    for (int i = beg; i < end; ++i) {
        float4 v = *reinterpret_cast<const float4*>(&H[(size_t)esrc[i] * ld_in + f]);
        acc.x += v.x; acc.y += v.y; acc.z += v.z; acc.w += v.w;
    }
    acc.x = fmaxf(acc.x, 0.f); acc.y = fmaxf(acc.y, 0.f);
    acc.z = fmaxf(acc.z, 0.f); acc.w = fmaxf(acc.w, 0.f);
    unsigned short h0 = f2bf(acc.x), h1 = f2bf(acc.y), h2 = f2bf(acc.z), h3 = f2bf(acc.w);
    unsigned short l0 = f2bf(acc.x - bf2f(h0));
    unsigned short l1 = f2bf(acc.y - bf2f(h1));
    unsigned short l2 = f2bf(acc.z - bf2f(h2));
    unsigned short l3 = f2bf(acc.w - bf2f(h3));
    *reinterpret_cast<ushort4*>(&Xhi[(size_t)node * kpad + f]) = make_ushort4(h0, h1, h2, h3);
    *reinterpret_cast<ushort4*>(&Xlo[(size_t)node * kpad + f]) = make_ushort4(l0, l1, l2, l3);
}

template <int ACT>
__global__ __launch_bounds__(128)
void aggregate_f4_kernel(const float* __restrict__ H, const int* __restrict__ row_start,
                         const int* __restrict__ esrc, float* __restrict__ out,
                         int d, int ld_in, int ld_out) {
    const int node = blockIdx.x;
    const int f = threadIdx.x * 4;
    if (f >= d) return;
    const int beg = row_start[node];
    const int end = row_start[node + 1];
    float4 acc = *reinterpret_cast<const float4*>(&H[(size_t)node * ld_in + f]);
    for (int i = beg; i < end; ++i) {
        float4 v = *reinterpret_cast<const float4*>(&H[(size_t)esrc[i] * ld_in + f]);
        acc.x += v.x; acc.y += v.y; acc.z += v.z; acc.w += v.w;
    }
    if (ACT == 1) {
        acc.x = fmaxf(acc.x, 0.f); acc.y = fmaxf(acc.y, 0.f);
        acc.z = fmaxf(acc.z, 0.f); acc.w = fmaxf(acc.w, 0.f);
    }
    if (ACT == 2) {
        acc.x = tanhf(acc.x); acc.y = tanhf(acc.y);
        acc.z = tanhf(acc.z); acc.w = tanhf(acc.w);
    }
    *reinterpret_cast<float4*>(&out[(size_t)node * ld_out + f]) = acc;
}

template <int ACT>
__global__ __launch_bounds__(64)
void aggregate_small_kernel(const float* __restrict__ H, const int* __restrict__ row_start,
                            const int* __restrict__ esrc, float* __restrict__ out,
                            int d, int ld_in, int ld_out) {
    const int node = blockIdx.x;
    const int f = threadIdx.x;
    if (f >= d) return;
    const int beg = row_start[node];
    const int end = row_start[node + 1];
    float acc = H[(size_t)node * ld_in + f];
    for (int i = beg; i < end; ++i)
        acc += H[(size_t)esrc[i] * ld_in + f];
    if (ACT == 1) acc = fmaxf(acc, 0.f);
    if (ACT == 2) acc = tanhf(acc);
    out[(size_t)node * ld_out + f] = acc;
}

template <int ACT>
__global__ __launch_bounds__(256)
void aggregate_kernel(const float* __restrict__ H, const int* __restrict__ row_start,
                      const int* __restrict__ esrc, float* __restrict__ out,
                      int d, int ld_in) {
    const int node = blockIdx.x;
    const int t = threadIdx.x;
    const int beg = row_start[node];
    const int end = row_start[node + 1];
    float acc[4] = {0.f, 0.f, 0.f, 0.f};
    #pragma unroll
    for (int j = 0; j < 4; ++j) {
        int f = t + j * 256;
        if (f < d) acc[j] = H[(size_t)node * ld_in + f];
    }
    for (int i = beg; i < end; ++i) {
        const size_t b = (size_t)esrc[i] * ld_in;
        #pragma unroll
        for (int j = 0; j < 4; ++j) {
            int f = t + j * 256;
            if (f < d) acc[j] += H[b + f];
        }
    }
    #pragma unroll
    for (int j = 0; j < 4; ++j) {
        int f = t + j * 256;
        if (f < d) {
            float v = acc[j];
            if (ACT == 1) v = fmaxf(v, 0.f);
            if (ACT == 2) v = tanhf(v);
            out[(size_t)node * d + f] = v;
        }
    }
}

// ---------------- launch ----------------

extern "C" void kernel_launch(void* const* d_in, const int* in_sizes, int n_in,
                              void* d_out, int out_size, void* d_ws, size_t ws_size,
                              hipStream_t stream) {
    const float* features = (const float*)d_in[0];
    const int*   src      = (const int*)d_in[1];
    const int*   dst      = (const int*)d_in[2];
    const float* W1 = (const float*)d_in[3];  const float* b1 = (const float*)d_in[4];
    const float* W2 = (const float*)d_in[5];  const float* b2 = (const float*)d_in[6];
    const float* W3 = (const float*)d_in[7];  const float* b3 = (const float*)d_in[8];
    const float* W4 = (const float*)d_in[9];  const float* b4 = (const float*)d_in[10];
    float* out = (float*)d_out;
    char* ws = (char*)d_ws;

    const size_t SZ_A    = (size_t)M_PAD * D_IN * 2;
    const size_t OFF_ALO = SZ_A;
    const size_t OFF_H1  = 2 * SZ_A;
    const size_t SZ_H1   = (size_t)M_PAD * LDH1 * 4;
    const size_t OFF_W1T = OFF_H1 + SZ_H1;
    const size_t SZ_W1T  = (size_t)N1_PAD * D_IN * 2;
    const size_t OFF_CSR = OFF_W1T + 2 * SZ_W1T;
    const size_t SZ_CSR  = (size_t)(N_NODES * 3 + 1 + N_EDGES) * 4;
    const size_t WS_NEED = OFF_CSR + SZ_CSR;

    const size_t SZ_X2   = (size_t)M_PAD * K2_PAD * 2;
    const size_t OFF_X2H = 0;
    const size_t OFF_X2L = SZ_X2;
    const size_t OFF_H2  = 2 * SZ_X2;
    const size_t OFF_X3  = OFF_H1;
    const size_t OFF_H3  = OFF_H1 + 24000000;
    const size_t OFF_X4  = OFF_H1 + 25600000;
    const size_t OFF_H4  = OFF_H1 + 27200000;
    const size_t OFF_W2T = OFF_H1 + 28800000;
    const size_t SZ_W2T  = (size_t)N2_PAD * K2_PAD * 2;

    const bool use_mfma = (ws_size >= WS_NEED);
    size_t csr_off = use_mfma ? OFF_CSR : (size_t)2 * N_NODES * 1000 * 4;
    int* counts    = (int*)(ws + csr_off);
    int* row_start = counts + N_NODES;
    int* cursor    = row_start + N_NODES + 1;
    int* esrc      = cursor + N_NODES;

    zero_counts_kernel<<<(N_NODES + 255) / 256, 256, 0, stream>>>(counts);
    count_kernel<<<(N_EDGES + 255) / 256, 256, 0, stream>>>(dst, counts);
    scan_kernel<<<1, 1024, 0, stream>>>(counts, row_start, cursor);
    scatter_kernel<<<(N_EDGES + 255) / 256, 256, 0, stream>>>(src, dst, cursor, esrc);

    if (use_mfma) {
        unsigned short* Ahi   = (unsigned short*)ws;
        unsigned short* Alo   = (unsigned short*)(ws + OFF_ALO);
        float*          H1    = (float*)(ws + OFF_H1);
        unsigned short* W1hiT = (unsigned short*)(ws + OFF_W1T);
        unsigned short* W1loT = (unsigned short*)(ws + OFF_W1T + SZ_W1T);
        unsigned short* X2hi  = (unsigned short*)(ws + OFF_X2H);
        unsigned short* X2lo  = (unsigned short*)(ws + OFF_X2L);
        float*          H2    = (float*)(ws + OFF_H2);
        float*          x3    = (float*)(ws + OFF_X3);
        float*          h3    = (float*)(ws + OFF_H3);
        float*          x4    = (float*)(ws + OFF_X4);
        float*          h4    = (float*)(ws + OFF_H4);
        unsigned short* W2hiT = (unsigned short*)(ws + OFF_W2T);
        unsigned short* W2loT = (unsigned short*)(ws + OFF_W2T + SZ_W2T);

        // Layer 1 (128^2, single-buffer rotation, parity-fixed swizzle)
        convA_kernel<<<(N_NODES * D_IN / 4 + 255) / 256, 256, 0, stream>>>(features, Ahi, Alo);
        convW_kernel<<<dim3(N1_PAD / 32, D_IN / 32), 256, 0, stream>>>(W1, W1hiT, W1loT, D_IN, 1000, D_IN);
        gemm_split_mfma_kernel<<<(N1_PAD / GBN) * (M_PAD / GBM), 256, 0, stream>>>(
            Ahi, Alo, W1hiT, W1loT, b1, H1, D_IN, N1_PAD / GBN, LDH1, 1000);
        aggregate_bf16_kernel<<<N_NODES, 256, 0, stream>>>(
            H1, row_start, esrc, X2hi, X2lo, 1000, LDH1, K2_PAD);

        // Layer 2 (128^2, single-buffer rotation)
        convW_kernel<<<dim3(N2_PAD / 32, K2_PAD / 32), 256, 0, stream>>>(W2, W2hiT, W2loT, 1000, 300, K2_PAD);
        gemm_split_mfma_kernel<<<(N2_PAD / GBN) * (M_PAD / GBM), 256, 0, stream>>>(
            X2hi, X2lo, W2hiT, W2loT, b2, H2, K2_PAD, N2_PAD / GBN, LDH2, 300);
        aggregate_f4_kernel<1><<<N_NODES, 128, 0, stream>>>(H2, row_start, esrc, x3, 300, LDH2, 300);

        // Layer 3
        dim3 g3((20 + BN - 1) / BN, (N_NODES + BM - 1) / BM);
        gemm_bias_kernel<<<g3, 256, 0, stream>>>(x3, W3, b3, h3, N_NODES, 20, 300);
        aggregate_small_kernel<0><<<N_NODES, 64, 0, stream>>>(h3, row_start, esrc, x4, 20, 20, 20);

        // Layer 4
        dim3 g4((10 + BN - 1) / BN, (N_NODES + BM - 1) / BM);
        gemm_bias_kernel<<<g4, 256, 0, stream>>>(x4, W4, b4, h4, N_NODES, 10, 20);
        aggregate_small_kernel<2><<<N_NODES, 64, 0, stream>>>(h4, row_start, esrc, out, 10, 10, 10);
    } else {
        const size_t BUF = (size_t)N_NODES * 1000 * 4;
        float* bufA = (float*)ws;
        float* bufB = (float*)(ws + BUF);

        dim3 g1((1000 + BN - 1) / BN, (N_NODES + BM - 1) / BM);
        gemm_bias_kernel<<<g1, 256, 0, stream>>>(features, W1, b1, bufA, N_NODES, 1000, D_IN);
        aggregate_kernel<1><<<N_NODES, 256, 0, stream>>>(bufA, row_start, esrc, bufB, 1000, 1000);

        dim3 g2((300 + BN - 1) / BN, (N_NODES + BM - 1) / BM);
        gemm_bias_kernel<<<g2, 256, 0, stream>>>(bufB, W2, b2, bufA, N_NODES, 300, 1000);
        aggregate_kernel<1><<<N_NODES, 256, 0, stream>>>(bufA, row_start, esrc, bufB, 300, 300);

        dim3 g3((20 + BN - 1) / BN, (N_NODES + BM - 1) / BM);
        gemm_bias_kernel<<<g3, 256, 0, stream>>>(bufB, W3, b3, bufA, N_NODES, 20, 300);
        aggregate_kernel<0><<<N_NODES, 256, 0, stream>>>(bufA, row_start, esrc, bufB, 20, 20);

        dim3 g4((10 + BN - 1) / BN, (N_NODES + BM - 1) / BM);
        gemm_bias_kernel<<<g4, 256, 0, stream>>>(bufB, W4, b4, bufA, N_NODES, 10, 20);
        aggregate_kernel<2><<<N_NODES, 256, 0, stream>>>(bufA, row_start, esrc, out, 10, 10);
    }
}

// Round 10
// 877.419 us; speedup vs baseline: 1.6118x; 1.6118x over previous
//
#include <hip/hip_runtime.h>
#include <math.h>

#define N_NODES 20000
#define N_EDGES 320000
#define D_IN    3072

#define M_PAD   20096   // 157 * 128
#define N1_PAD  1024
#define LDH1    1024
#define K2_PAD  1024
#define N2_PAD  384
#define LDH2    384

typedef short bf16x8 __attribute__((ext_vector_type(8)));
typedef float f32x4  __attribute__((ext_vector_type(4)));

#define GLOAD_LDS16(g, l) __builtin_amdgcn_global_load_lds( \
    (const __attribute__((address_space(1))) void*)(g),     \
    (__attribute__((address_space(3))) void*)(l), 16, 0, 0)

__device__ inline unsigned short f2bf(float x) {
    union { float f; unsigned u; } v; v.f = x;
    unsigned r = (v.u + 0x7FFFu + ((v.u >> 16) & 1u)) >> 16;
    return (unsigned short)r;
}
__device__ inline float bf2f(unsigned short h) {
    union { float f; unsigned u; } v; v.u = ((unsigned)h) << 16;
    return v.f;
}

// ---------------- CSR build ----------------

__global__ void zero_counts_kernel(int* __restrict__ counts) {
    int i = blockIdx.x * blockDim.x + threadIdx.x;
    if (i < N_NODES) counts[i] = 0;
}

__global__ void count_kernel(const int* __restrict__ dst, int* __restrict__ counts) {
    int e = blockIdx.x * blockDim.x + threadIdx.x;
    if (e < N_EDGES) atomicAdd(&counts[dst[e]], 1);
}

__global__ void scan_kernel(const int* __restrict__ counts, int* __restrict__ row_start,
                            int* __restrict__ cursor) {
    __shared__ int part[1024];
    const int T = 1024;
    int t = threadIdx.x;
    const int chunk = (N_NODES + T - 1) / T;
    int lo = t * chunk;
    int hi = lo + chunk; if (hi > N_NODES) hi = N_NODES;
    int s = 0;
    for (int i = lo; i < hi; ++i) s += counts[i];
    part[t] = s;
    __syncthreads();
    for (int off = 1; off < T; off <<= 1) {
        int v = (t >= off) ? part[t - off] : 0;
        __syncthreads();
        part[t] += v;
        __syncthreads();
    }
    int run = part[t] - s;
    for (int i = lo; i < hi; ++i) {
        row_start[i] = run;
        cursor[i] = run;
        run += counts[i];
    }
    if (t == T - 1) row_start[N_NODES] = run;
}

__global__ void scatter_kernel(const int* __restrict__ src, const int* __restrict__ dst,
                               int* __restrict__ cursor, int* __restrict__ esrc) {
    int e = blockIdx.x * blockDim.x + threadIdx.x;
    if (e < N_EDGES) {
        int pos = atomicAdd(&cursor[dst[e]], 1);
        esrc[pos] = src[e];
    }
}

// ---------------- conversions ----------------

__global__ __launch_bounds__(256)
void convA_kernel(const float* __restrict__ X, unsigned short* __restrict__ Ahi,
                  unsigned short* __restrict__ Alo) {
    int i = blockIdx.x * blockDim.x + threadIdx.x;
    const int total = N_NODES * D_IN / 4;
    if (i >= total) return;
    float4 v = reinterpret_cast<const float4*>(X)[i];
    unsigned short h0 = f2bf(v.x), h1 = f2bf(v.y), h2 = f2bf(v.z), h3 = f2bf(v.w);
    unsigned short l0 = f2bf(v.x - bf2f(h0));
    unsigned short l1 = f2bf(v.y - bf2f(h1));
    unsigned short l2 = f2bf(v.z - bf2f(h2));
    unsigned short l3 = f2bf(v.w - bf2f(h3));
    reinterpret_cast<ushort4*>(Ahi)[i] = make_ushort4(h0, h1, h2, h3);
    reinterpret_cast<ushort4*>(Alo)[i] = make_ushort4(l0, l1, l2, l3);
}

__global__ __launch_bounds__(256)
void convW_kernel(const float* __restrict__ W, unsigned short* __restrict__ WhiT,
                  unsigned short* __restrict__ WloT, int K, int N, int K_PAD) {
    __shared__ float sh[32][33];
    const int t  = threadIdx.x;
    const int tx = t & 31;
    const int ty = t >> 5;
    const int n0 = blockIdx.x * 32;
    const int k0 = blockIdx.y * 32;
    #pragma unroll
    for (int it = 0; it < 4; ++it) {
        int k = k0 + ty + it * 8;
        int n = n0 + tx;
        sh[ty + it * 8][tx] = (k < K && n < N) ? W[(long)k * N + n] : 0.f;
    }
    __syncthreads();
    #pragma unroll
    for (int it = 0; it < 4; ++it) {
        int n = n0 + ty + it * 8;
        int k = k0 + tx;
        float v = sh[tx][ty + it * 8];
        unsigned short h = f2bf(v);
        unsigned short l = f2bf(v - bf2f(h));
        WhiT[(long)n * K_PAD + k] = h;
        WloT[(long)n * K_PAD + k] = l;
    }
}

// ---------------- split-bf16 MFMA GEMM, 3-phase single-buffer + parity-fixed swizzle ----------------
// H = Ahi*Bhi + Ahi*Blo + Alo*Bhi + bias.
// r9 verified: ((r>>1)&3) slot-select -> SQ_LDS_BANK_CONFLICT = 0 (row's bank set
// keyed by r&1; slot index decorrelated from parity spreads 8 same-parity lanes
// across all 4 16B slots -> 2 lanes/bank-quad = free).
// r9 lesson: launch_bounds(256,4) capped VGPR at 64 -> scratch spill -> 1.3 GB
// HBM write traffic. Use (256,3): VGPR 84, zero spill (r7-proven).
// Schedule (verified r7): single 32KB buffer, slot rotation, derived vmcnt gates:
//   p1(t): gate vmcnt(2) [t=0: 4]; read Ahi,Bhi; issue Alo(t) [t>0]
//   p2(t): gate vmcnt(2);          read Blo;     issue Ahi,Bhi(t+1) [t<NT-1]
//   p3(t): gate vmcnt(4) [last:0]; read Alo;     issue Blo(t+1)     [t<NT-1]

#define GBM 128
#define GBN 128
#define GBK 32

#define ISSUE2(p0, p1, ss) do { \
    GLOAD_LDS16(p0, &lds[ss][wid * 1024]); \
    GLOAD_LDS16(p1, &lds[ss][wid * 1024 + 4096]); \
    p0 += GBK; p1 += GBK; } while (0)

__global__ __launch_bounds__(256, 3)
void gemm_split_mfma_kernel(const unsigned short* __restrict__ Ahi,
                            const unsigned short* __restrict__ Alo,
                            const unsigned short* __restrict__ BhiT,
                            const unsigned short* __restrict__ BloT,
                            const float* __restrict__ bias, float* __restrict__ H,
                            int K, int NB, int ldh, int nbias) {
    // slots: 0=Ahi 1=Alo 2=Bhi 3=Blo (8KB each, single copy)
    __shared__ __align__(16) char lds[4][8192];

    const int t    = threadIdx.x;
    const int wid  = t >> 6;
    const int lane = t & 63;
    const int wr   = wid >> 1;
    const int wc   = wid & 1;

    // bijective XCD swizzle
    const int orig = blockIdx.x;
    const int nwg  = gridDim.x;
    const int xcd  = orig & 7, loc = orig >> 3;
    const int q    = nwg >> 3, r = nwg & 7;
    const int wgid = (xcd < r ? xcd * (q + 1) : r * (q + 1) + (xcd - r) * q) + loc;
    const int m0   = (wgid / NB) * GBM;
    const int n0   = (wgid % NB) * GBN;

    f32x4 acc[4][4] = {};

    const int byt0 = wid * 1024 + lane * 16;
    const int byt1 = byt0 + 4096;
    const int r0 = byt0 >> 6, r1 = byt1 >> 6;
    const int cs0 = (byt0 & 63) ^ (((r0 >> 1) & 3) << 4);   // parity-independent slot
    const int cs1 = (byt1 & 63) ^ (((r1 >> 1) & 3) << 4);

    const unsigned short* pAh0 = Ahi  + (size_t)(m0 + r0) * K + (cs0 >> 1);
    const unsigned short* pAh1 = Ahi  + (size_t)(m0 + r1) * K + (cs1 >> 1);
    const unsigned short* pAl0 = Alo  + (size_t)(m0 + r0) * K + (cs0 >> 1);
    const unsigned short* pAl1 = Alo  + (size_t)(m0 + r1) * K + (cs1 >> 1);
    const unsigned short* pBh0 = BhiT + (size_t)(n0 + r0) * K + (cs0 >> 1);
    const unsigned short* pBh1 = BhiT + (size_t)(n0 + r1) * K + (cs1 >> 1);
    const unsigned short* pBl0 = BloT + (size_t)(n0 + r0) * K + (cs0 >> 1);
    const unsigned short* pBl1 = BloT + (size_t)(n0 + r1) * K + (cs1 >> 1);

    const int fr   = lane & 15;
    const int kbs  = ((lane >> 4) << 4) ^ (((fr >> 1) & 3) << 4); // parity-independent
    const int arow = wr * 64;
    const int brow = wc * 64;

    // prologue: tile 0 fully issued (8 instrs/thread), order Ahi,Bhi,Blo,Alo
    ISSUE2(pAh0, pAh1, 0);
    ISSUE2(pBh0, pBh1, 2);
    ISSUE2(pBl0, pBl1, 3);
    ISSUE2(pAl0, pAl1, 1);

    const int NT = K >> 5;
    bf16x8 ahi[4], bhi[4], blo[4], alo[4];

    for (int tt = 0; tt < NT; ++tt) {
        // ---- phase 1: hi*hi ----
        if (tt == 0) asm volatile("s_waitcnt vmcnt(4)" ::: "memory");
        else         asm volatile("s_waitcnt vmcnt(2)" ::: "memory");
        __builtin_amdgcn_s_barrier();
        #pragma unroll
        for (int i = 0; i < 4; ++i)
            ahi[i] = *(const bf16x8*)(&lds[0][(arow + i * 16 + fr) * 64 + kbs]);
        #pragma unroll
        for (int j = 0; j < 4; ++j)
            bhi[j] = *(const bf16x8*)(&lds[2][(brow + j * 16 + fr) * 64 + kbs]);
        if (tt > 0) ISSUE2(pAl0, pAl1, 1);     // Alo(t): last read of Alo(t-1) was p3(t-1)
        __builtin_amdgcn_s_setprio(1);
        #pragma unroll
        for (int i = 0; i < 4; ++i)
            #pragma unroll
            for (int j = 0; j < 4; ++j)
                acc[i][j] = __builtin_amdgcn_mfma_f32_16x16x32_bf16(ahi[i], bhi[j], acc[i][j], 0, 0, 0);
        __builtin_amdgcn_s_setprio(0);
        // ---- phase 2: hi*lo ----
        asm volatile("s_waitcnt vmcnt(2)" ::: "memory");
        __builtin_amdgcn_s_barrier();
        #pragma unroll
        for (int j = 0; j < 4; ++j)
            blo[j] = *(const bf16x8*)(&lds[3][(brow + j * 16 + fr) * 64 + kbs]);
        if (tt < NT - 1) {                     // Ahi/Bhi(t+1): last reads were p1(t)
            ISSUE2(pAh0, pAh1, 0);
            ISSUE2(pBh0, pBh1, 2);
        }
        __builtin_amdgcn_s_setprio(1);
        #pragma unroll
        for (int i = 0; i < 4; ++i)
            #pragma unroll
            for (int j = 0; j < 4; ++j)
                acc[i][j] = __builtin_amdgcn_mfma_f32_16x16x32_bf16(ahi[i], blo[j], acc[i][j], 0, 0, 0);
        __builtin_amdgcn_s_setprio(0);
        // ---- phase 3: lo*hi ----
        if (tt < NT - 1) asm volatile("s_waitcnt vmcnt(4)" ::: "memory");
        else             asm volatile("s_waitcnt vmcnt(0)" ::: "memory");
        __builtin_amdgcn_s_barrier();
        #pragma unroll
        for (int i = 0; i < 4; ++i)
            alo[i] = *(const bf16x8*)(&lds[1][(arow + i * 16 + fr) * 64 + kbs]);
        if (tt < NT - 1) ISSUE2(pBl0, pBl1, 3); // Blo(t+1): last read was p2(t)
        __builtin_amdgcn_s_setprio(1);
        #pragma unroll
        for (int i = 0; i < 4; ++i)
            #pragma unroll
            for (int j = 0; j < 4; ++j)
                acc[i][j] = __builtin_amdgcn_mfma_f32_16x16x32_bf16(alo[i], bhi[j], acc[i][j], 0, 0, 0);
        __builtin_amdgcn_s_setprio(0);
    }

    // epilogue: C layout col = lane&15, row = (lane>>4)*4 + reg
    #pragma unroll
    for (int i = 0; i < 4; ++i) {
        #pragma unroll
        for (int j = 0; j < 4; ++j) {
            int row = m0 + wr * 64 + i * 16 + (lane >> 4) * 4;
            int col = n0 + wc * 64 + j * 16 + (lane & 15);
            float bv = (col < nbias) ? bias[col] : 0.f;
            #pragma unroll
            for (int r2 = 0; r2 < 4; ++r2)
                H[(size_t)(row + r2) * ldh + col] = acc[i][j][r2] + bv;
        }
    }
}

// ---------------- fp32 tiled GEMM (layers 3-4 + fallback) ----------------

#define BM 64
#define BN 64
#define BKT 16
#define TM 4
#define TN 4

__global__ __launch_bounds__(256)
void gemm_bias_kernel(const float* __restrict__ X, const float* __restrict__ W,
                      const float* __restrict__ bias, float* __restrict__ H,
                      int M, int N, int K) {
    __shared__ float As[BKT][BM];
    __shared__ float Bs[BKT][BN];

    const int t  = threadIdx.x;
    const int tx = t & 15;
    const int ty = t >> 4;
    const int m0 = blockIdx.y * BM;
    const int n0 = blockIdx.x * BN;

    float acc[TM][TN] = {};

    const int arow = t >> 2;
    const int ak0  = (t & 3) * 4;
    const int brow = t >> 4;
    const int bn0  = (t & 15) * 4;

    for (int k0 = 0; k0 < K; k0 += BKT) {
        {
            float4 v = make_float4(0.f, 0.f, 0.f, 0.f);
            int gm = m0 + arow;
            int gk = k0 + ak0;
            if (gm < M) {
                if (gk + 3 < K) {
                    v = *reinterpret_cast<const float4*>(&X[(long)gm * K + gk]);
                } else {
                    float tmp[4] = {0.f, 0.f, 0.f, 0.f};
                    for (int i = 0; i < 4; ++i)
                        if (gk + i < K) tmp[i] = X[(long)gm * K + gk + i];
                    v = make_float4(tmp[0], tmp[1], tmp[2], tmp[3]);
                }
            }
            As[ak0 + 0][arow] = v.x;
            As[ak0 + 1][arow] = v.y;
            As[ak0 + 2][arow] = v.z;
            As[ak0 + 3][arow] = v.w;
        }
        {
            float4 v = make_float4(0.f, 0.f, 0.f, 0.f);
            int gk = k0 + brow;
            int gn = n0 + bn0;
            if (gk < K) {
                if (gn + 3 < N) {
                    v = *reinterpret_cast<const float4*>(&W[(long)gk * N + gn]);
                } else {
                    float tmp[4] = {0.f, 0.f, 0.f, 0.f};
                    for (int i = 0; i < 4; ++i)
                        if (gn + i < N) tmp[i] = W[(long)gk * N + gn + i];
                    v = make_float4(tmp[0], tmp[1], tmp[2], tmp[3]);
                }
            }
            *reinterpret_cast<float4*>(&Bs[brow][bn0]) = v;
        }
        __syncthreads();

        #pragma unroll
        for (int kk = 0; kk < BKT; ++kk) {
            float a[TM], b[TN];
            *reinterpret_cast<float4*>(a) = *reinterpret_cast<const float4*>(&As[kk][ty * TM]);
            *reinterpret_cast<float4*>(b) = *reinterpret_cast<const float4*>(&Bs[kk][tx * TN]);
            #pragma unroll
            for (int i = 0; i < TM; ++i)
                #pragma unroll
                for (int j = 0; j < TN; ++j)
                    acc[i][j] += a[i] * b[j];
        }
        __syncthreads();
    }

    #pragma unroll
    for (int i = 0; i < TM; ++i) {
        int gm = m0 + ty * TM + i;
        if (gm >= M) continue;
        #pragma unroll
        for (int j = 0; j < TN; ++j) {
            int gn = n0 + tx * TN + j;
            if (gn < N) H[(long)gm * N + gn] = acc[i][j] + bias[gn];
        }
    }
}

// ---------------- aggregates ----------------

__global__ __launch_bounds__(256)
void aggregate_bf16_kernel(const float* __restrict__ H, const int* __restrict__ row_start,
                           const int* __restrict__ esrc, unsigned short* __restrict__ Xhi,
                           unsigned short* __restrict__ Xlo, int d, int ld_in, int kpad) {
    const int node = blockIdx.x;
    const int f = threadIdx.x * 4;
    if (f >= kpad) return;
    if (f >= d) {
        ushort4 z = make_ushort4(0, 0, 0, 0);
        *reinterpret_cast<ushort4*>(&Xhi[(size_t)node * kpad + f]) = z;
        *reinterpret_cast<ushort4*>(&Xlo[(size_t)node * kpad + f]) = z;
        return;
    }
    const int beg = row_start[node];
    const int end = row_start[node + 1];
    float4 acc = *reinterpret_cast<const float4*>(&H[(size_t)node * ld_in + f]);
    for (int i = beg; i < end; ++i) {
        float4 v = *reinterpret_cast<const float4*>(&H[(size_t)esrc[i] * ld_in + f]);
        acc.x += v.x; acc.y += v.y; acc.z += v.z; acc.w += v.w;
    }
    acc.x = fmaxf(acc.x, 0.f); acc.y = fmaxf(acc.y, 0.f);
    acc.z = fmaxf(acc.z, 0.f); acc.w = fmaxf(acc.w, 0.f);
    unsigned short h0 = f2bf(acc.x), h1 = f2bf(acc.y), h2 = f2bf(acc.z), h3 = f2bf(acc.w);
    unsigned short l0 = f2bf(acc.x - bf2f(h0));
    unsigned short l1 = f2bf(acc.y - bf2f(h1));
    unsigned short l2 = f2bf(acc.z - bf2f(h2));
    unsigned short l3 = f2bf(acc.w - bf2f(h3));
    *reinterpret_cast<ushort4*>(&Xhi[(size_t)node * kpad + f]) = make_ushort4(h0, h1, h2, h3);
    *reinterpret_cast<ushort4*>(&Xlo[(size_t)node * kpad + f]) = make_ushort4(l0, l1, l2, l3);
}

template <int ACT>
__global__ __launch_bounds__(128)
void aggregate_f4_kernel(const float* __restrict__ H, const int* __restrict__ row_start,
                         const int* __restrict__ esrc, float* __restrict__ out,
                         int d, int ld_in, int ld_out) {
    const int node = blockIdx.x;
    const int f = threadIdx.x * 4;
    if (f >= d) return;
    const int beg = row_start[node];
    const int end = row_start[node + 1];
    float4 acc = *reinterpret_cast<const float4*>(&H[(size_t)node * ld_in + f]);
    for (int i = beg; i < end; ++i) {
        float4 v = *reinterpret_cast<const float4*>(&H[(size_t)esrc[i] * ld_in + f]);
        acc.x += v.x; acc.y += v.y; acc.z += v.z; acc.w += v.w;
    }
    if (ACT == 1) {
        acc.x = fmaxf(acc.x, 0.f); acc.y = fmaxf(acc.y, 0.f);
        acc.z = fmaxf(acc.z, 0.f); acc.w = fmaxf(acc.w, 0.f);
    }
    if (ACT == 2) {
        acc.x = tanhf(acc.x); acc.y = tanhf(acc.y);
        acc.z = tanhf(acc.z); acc.w = tanhf(acc.w);
    }
    *reinterpret_cast<float4*>(&out[(size_t)node * ld_out + f]) = acc;
}

template <int ACT>
__global__ __launch_bounds__(64)
void aggregate_small_kernel(const float* __restrict__ H, const int* __restrict__ row_start,
                            const int* __restrict__ esrc, float* __restrict__ out,
                            int d, int ld_in, int ld_out) {
    const int node = blockIdx.x;
    const int f = threadIdx.x;
    if (f >= d) return;
    const int beg = row_start[node];
    const int end = row_start[node + 1];
    float acc = H[(size_t)node * ld_in + f];
    for (int i = beg; i < end; ++i)
        acc += H[(size_t)esrc[i] * ld_in + f];
    if (ACT == 1) acc = fmaxf(acc, 0.f);
    if (ACT == 2) acc = tanhf(acc);
    out[(size_t)node * ld_out + f] = acc;
}

template <int ACT>
__global__ __launch_bounds__(256)
void aggregate_kernel(const float* __restrict__ H, const int* __restrict__ row_start,
                      const int* __restrict__ esrc, float* __restrict__ out,
                      int d, int ld_in) {
    const int node = blockIdx.x;
    const int t = threadIdx.x;
    const int beg = row_start[node];
    const int end = row_start[node + 1];
    float acc[4] = {0.f, 0.f, 0.f, 0.f};
    #pragma unroll
    for (int j = 0; j < 4; ++j) {
        int f = t + j * 256;
        if (f < d) acc[j] = H[(size_t)node * ld_in + f];
    }
    for (int i = beg; i < end; ++i) {
        const size_t b = (size_t)esrc[i] * ld_in;
        #pragma unroll
        for (int j = 0; j < 4; ++j) {
            int f = t + j * 256;
            if (f < d) acc[j] += H[b + f];
        }
    }
    #pragma unroll
    for (int j = 0; j < 4; ++j) {
        int f = t + j * 256;
        if (f < d) {
            float v = acc[j];
            if (ACT == 1) v = fmaxf(v, 0.f);
            if (ACT == 2) v = tanhf(v);
            out[(size_t)node * d + f] = v;
        }
    }
}

// ---------------- launch ----------------

extern "C" void kernel_launch(void* const* d_in, const int* in_sizes, int n_in,
                              void* d_out, int out_size, void* d_ws, size_t ws_size,
                              hipStream_t stream) {
    const float* features = (const float*)d_in[0];
    const int*   src      = (const int*)d_in[1];
    const int*   dst      = (const int*)d_in[2];
    const float* W1 = (const float*)d_in[3];  const float* b1 = (const float*)d_in[4];
    const float* W2 = (const float*)d_in[5];  const float* b2 = (const float*)d_in[6];
    const float* W3 = (const float*)d_in[7];  const float* b3 = (const float*)d_in[8];
    const float* W4 = (const float*)d_in[9];  const float* b4 = (const float*)d_in[10];
    float* out = (float*)d_out;
    char* ws = (char*)d_ws;

    const size_t SZ_A    = (size_t)M_PAD * D_IN * 2;
    const size_t OFF_ALO = SZ_A;
    const size_t OFF_H1  = 2 * SZ_A;
    const size_t SZ_H1   = (size_t)M_PAD * LDH1 * 4;
    const size_t OFF_W1T = OFF_H1 + SZ_H1;
    const size_t SZ_W1T  = (size_t)N1_PAD * D_IN * 2;
    const size_t OFF_CSR = OFF_W1T + 2 * SZ_W1T;
    const size_t SZ_CSR  = (size_t)(N_NODES * 3 + 1 + N_EDGES) * 4;
    const size_t WS_NEED = OFF_CSR + SZ_CSR;

    const size_t SZ_X2   = (size_t)M_PAD * K2_PAD * 2;
    const size_t OFF_X2H = 0;
    const size_t OFF_X2L = SZ_X2;
    const size_t OFF_H2  = 2 * SZ_X2;
    const size_t OFF_X3  = OFF_H1;
    const size_t OFF_H3  = OFF_H1 + 24000000;
    const size_t OFF_X4  = OFF_H1 + 25600000;
    const size_t OFF_H4  = OFF_H1 + 27200000;
    const size_t OFF_W2T = OFF_H1 + 28800000;
    const size_t SZ_W2T  = (size_t)N2_PAD * K2_PAD * 2;

    const bool use_mfma = (ws_size >= WS_NEED);
    size_t csr_off = use_mfma ? OFF_CSR : (size_t)2 * N_NODES * 1000 * 4;
    int* counts    = (int*)(ws + csr_off);
    int* row_start = counts + N_NODES;
    int* cursor    = row_start + N_NODES + 1;
    int* esrc      = cursor + N_NODES;

    zero_counts_kernel<<<(N_NODES + 255) / 256, 256, 0, stream>>>(counts);
    count_kernel<<<(N_EDGES + 255) / 256, 256, 0, stream>>>(dst, counts);
    scan_kernel<<<1, 1024, 0, stream>>>(counts, row_start, cursor);
    scatter_kernel<<<(N_EDGES + 255) / 256, 256, 0, stream>>>(src, dst, cursor, esrc);

    if (use_mfma) {
        unsigned short* Ahi   = (unsigned short*)ws;
        unsigned short* Alo   = (unsigned short*)(ws + OFF_ALO);
        float*          H1    = (float*)(ws + OFF_H1);
        unsigned short* W1hiT = (unsigned short*)(ws + OFF_W1T);
        unsigned short* W1loT = (unsigned short*)(ws + OFF_W1T + SZ_W1T);
        unsigned short* X2hi  = (unsigned short*)(ws + OFF_X2H);
        unsigned short* X2lo  = (unsigned short*)(ws + OFF_X2L);
        float*          H2    = (float*)(ws + OFF_H2);
        float*          x3    = (float*)(ws + OFF_X3);
        float*          h3    = (float*)(ws + OFF_H3);
        float*          x4    = (float*)(ws + OFF_X4);
        float*          h4    = (float*)(ws + OFF_H4);
        unsigned short* W2hiT = (unsigned short*)(ws + OFF_W2T);
        unsigned short* W2loT = (unsigned short*)(ws + OFF_W2T + SZ_W2T);

        // Layer 1 (128^2, single-buffer rotation, zero-conflict swizzle)
        convA_kernel<<<(N_NODES * D_IN / 4 + 255) / 256, 256, 0, stream>>>(features, Ahi, Alo);
        convW_kernel<<<dim3(N1_PAD / 32, D_IN / 32), 256, 0, stream>>>(W1, W1hiT, W1loT, D_IN, 1000, D_IN);
        gemm_split_mfma_kernel<<<(N1_PAD / GBN) * (M_PAD / GBM), 256, 0, stream>>>(
            Ahi, Alo, W1hiT, W1loT, b1, H1, D_IN, N1_PAD / GBN, LDH1, 1000);
        aggregate_bf16_kernel<<<N_NODES, 256, 0, stream>>>(
            H1, row_start, esrc, X2hi, X2lo, 1000, LDH1, K2_PAD);

        // Layer 2 (128^2, single-buffer rotation)
        convW_kernel<<<dim3(N2_PAD / 32, K2_PAD / 32), 256, 0, stream>>>(W2, W2hiT, W2loT, 1000, 300, K2_PAD);
        gemm_split_mfma_kernel<<<(N2_PAD / GBN) * (M_PAD / GBM), 256, 0, stream>>>(
            X2hi, X2lo, W2hiT, W2loT, b2, H2, K2_PAD, N2_PAD / GBN, LDH2, 300);
        aggregate_f4_kernel<1><<<N_NODES, 128, 0, stream>>>(H2, row_start, esrc, x3, 300, LDH2, 300);

        // Layer 3
        dim3 g3((20 + BN - 1) / BN, (N_NODES + BM - 1) / BM);
        gemm_bias_kernel<<<g3, 256, 0, stream>>>(x3, W3, b3, h3, N_NODES, 20, 300);
        aggregate_small_kernel<0><<<N_NODES, 64, 0, stream>>>(h3, row_start, esrc, x4, 20, 20, 20);

        // Layer 4
        dim3 g4((10 + BN - 1) / BN, (N_NODES + BM - 1) / BM);
        gemm_bias_kernel<<<g4, 256, 0, stream>>>(x4, W4, b4, h4, N_NODES, 10, 20);
        aggregate_small_kernel<2><<<N_NODES, 64, 0, stream>>>(h4, row_start, esrc, out, 10, 10, 10);
    } else {
        const size_t BUF = (size_t)N_NODES * 1000 * 4;
        float* bufA = (float*)ws;
        float* bufB = (float*)(ws + BUF);

        dim3 g1((1000 + BN - 1) / BN, (N_NODES + BM - 1) / BM);
        gemm_bias_kernel<<<g1, 256, 0, stream>>>(features, W1, b1, bufA, N_NODES, 1000, D_IN);
        aggregate_kernel<1><<<N_NODES, 256, 0, stream>>>(bufA, row_start, esrc, bufB, 1000, 1000);

        dim3 g2((300 + BN - 1) / BN, (N_NODES + BM - 1) / BM);
        gemm_bias_kernel<<<g2, 256, 0, stream>>>(bufB, W2, b2, bufA, N_NODES, 300, 1000);
        aggregate_kernel<1><<<N_NODES, 256, 0, stream>>>(bufA, row_start, esrc, bufB, 300, 300);

        dim3 g3((20 + BN - 1) / BN, (N_NODES + BM - 1) / BM);
        gemm_bias_kernel<<<g3, 256, 0, stream>>>(bufB, W3, b3, bufA, N_NODES, 20, 300);
        aggregate_kernel<0><<<N_NODES, 256, 0, stream>>>(bufA, row_start, esrc, bufB, 20, 20);

        dim3 g4((10 + BN - 1) / BN, (N_NODES + BM - 1) / BM);
        gemm_bias_kernel<<<g4, 256, 0, stream>>>(bufB, W4, b4, bufA, N_NODES, 10, 20);
        aggregate_kernel<2><<<N_NODES, 256, 0, stream>>>(bufA, row_start, esrc, out, 10, 10);
    }
}

// Round 11
// 851.876 us; speedup vs baseline: 1.6601x; 1.0300x over previous
//
#include <hip/hip_runtime.h>
#include <math.h>

#define N_NODES 20000
#define N_EDGES 320000
#define D_IN    3072

#define M_PAD   20096   // 157 * 128
#define N1_PAD  1024
#define LDH1    1024
#define K2_PAD  1024
#define N2_PAD  384
#define LDH2    384

typedef short bf16x8 __attribute__((ext_vector_type(8)));
typedef float f32x4  __attribute__((ext_vector_type(4)));

#define GLOAD_LDS16(g, l) __builtin_amdgcn_global_load_lds( \
    (const __attribute__((address_space(1))) void*)(g),     \
    (__attribute__((address_space(3))) void*)(l), 16, 0, 0)

__device__ inline unsigned short f2bf(float x) {
    union { float f; unsigned u; } v; v.f = x;
    unsigned r = (v.u + 0x7FFFu + ((v.u >> 16) & 1u)) >> 16;
    return (unsigned short)r;
}
__device__ inline float bf2f(unsigned short h) {
    union { float f; unsigned u; } v; v.u = ((unsigned)h) << 16;
    return v.f;
}

// ---------------- CSR build ----------------

__global__ void zero_counts_kernel(int* __restrict__ counts) {
    int i = blockIdx.x * blockDim.x + threadIdx.x;
    if (i < N_NODES) counts[i] = 0;
}

__global__ void count_kernel(const int* __restrict__ dst, int* __restrict__ counts) {
    int e = blockIdx.x * blockDim.x + threadIdx.x;
    if (e < N_EDGES) atomicAdd(&counts[dst[e]], 1);
}

__global__ void scan_kernel(const int* __restrict__ counts, int* __restrict__ row_start,
                            int* __restrict__ cursor) {
    __shared__ int part[1024];
    const int T = 1024;
    int t = threadIdx.x;
    const int chunk = (N_NODES + T - 1) / T;
    int lo = t * chunk;
    int hi = lo + chunk; if (hi > N_NODES) hi = N_NODES;
    int s = 0;
    for (int i = lo; i < hi; ++i) s += counts[i];
    part[t] = s;
    __syncthreads();
    for (int off = 1; off < T; off <<= 1) {
        int v = (t >= off) ? part[t - off] : 0;
        __syncthreads();
        part[t] += v;
        __syncthreads();
    }
    int run = part[t] - s;
    for (int i = lo; i < hi; ++i) {
        row_start[i] = run;
        cursor[i] = run;
        run += counts[i];
    }
    if (t == T - 1) row_start[N_NODES] = run;
}

__global__ void scatter_kernel(const int* __restrict__ src, const int* __restrict__ dst,
                               int* __restrict__ cursor, int* __restrict__ esrc) {
    int e = blockIdx.x * blockDim.x + threadIdx.x;
    if (e < N_EDGES) {
        int pos = atomicAdd(&cursor[dst[e]], 1);
        esrc[pos] = src[e];
    }
}

// ---------------- conversions ----------------

__global__ __launch_bounds__(256)
void convA_kernel(const float* __restrict__ X, unsigned short* __restrict__ Ahi,
                  unsigned short* __restrict__ Alo) {
    int i = blockIdx.x * blockDim.x + threadIdx.x;
    const int total = N_NODES * D_IN / 4;
    if (i >= total) return;
    float4 v = reinterpret_cast<const float4*>(X)[i];
    unsigned short h0 = f2bf(v.x), h1 = f2bf(v.y), h2 = f2bf(v.z), h3 = f2bf(v.w);
    unsigned short l0 = f2bf(v.x - bf2f(h0));
    unsigned short l1 = f2bf(v.y - bf2f(h1));
    unsigned short l2 = f2bf(v.z - bf2f(h2));
    unsigned short l3 = f2bf(v.w - bf2f(h3));
    reinterpret_cast<ushort4*>(Ahi)[i] = make_ushort4(h0, h1, h2, h3);
    reinterpret_cast<ushort4*>(Alo)[i] = make_ushort4(l0, l1, l2, l3);
}

__global__ __launch_bounds__(256)
void convW_kernel(const float* __restrict__ W, unsigned short* __restrict__ WhiT,
                  unsigned short* __restrict__ WloT, int K, int N, int K_PAD) {
    __shared__ float sh[32][33];
    const int t  = threadIdx.x;
    const int tx = t & 31;
    const int ty = t >> 5;
    const int n0 = blockIdx.x * 32;
    const int k0 = blockIdx.y * 32;
    #pragma unroll
    for (int it = 0; it < 4; ++it) {
        int k = k0 + ty + it * 8;
        int n = n0 + tx;
        sh[ty + it * 8][tx] = (k < K && n < N) ? W[(long)k * N + n] : 0.f;
    }
    __syncthreads();
    #pragma unroll
    for (int it = 0; it < 4; ++it) {
        int n = n0 + ty + it * 8;
        int k = k0 + tx;
        float v = sh[tx][ty + it * 8];
        unsigned short h = f2bf(v);
        unsigned short l = f2bf(v - bf2f(h));
        WhiT[(long)n * K_PAD + k] = h;
        WloT[(long)n * K_PAD + k] = l;
    }
}

// ---------------- split-bf16 MFMA GEMM (r10-verified: 365 us, 0 bank conflicts) ----------------
// H = Ahi*Bhi + Ahi*Blo + Alo*Bhi + bias.
// Parity-independent swizzle ((r>>1)&3): SQ_LDS_BANK_CONFLICT = 0 (r10).
// launch_bounds(256,3): VGPR 84, zero spill ((256,4) caps VGPR at 64 -> spills, r9).
// Single 32KB buffer, slot rotation, derived never-drain vmcnt gates (r7).

#define GBM 128
#define GBN 128
#define GBK 32

#define ISSUE2(p0, p1, ss) do { \
    GLOAD_LDS16(p0, &lds[ss][wid * 1024]); \
    GLOAD_LDS16(p1, &lds[ss][wid * 1024 + 4096]); \
    p0 += GBK; p1 += GBK; } while (0)

__global__ __launch_bounds__(256, 3)
void gemm_split_mfma_kernel(const unsigned short* __restrict__ Ahi,
                            const unsigned short* __restrict__ Alo,
                            const unsigned short* __restrict__ BhiT,
                            const unsigned short* __restrict__ BloT,
                            const float* __restrict__ bias, float* __restrict__ H,
                            int K, int NB, int ldh, int nbias) {
    __shared__ __align__(16) char lds[4][8192];

    const int t    = threadIdx.x;
    const int wid  = t >> 6;
    const int lane = t & 63;
    const int wr   = wid >> 1;
    const int wc   = wid & 1;

    const int orig = blockIdx.x;
    const int nwg  = gridDim.x;
    const int xcd  = orig & 7, loc = orig >> 3;
    const int q    = nwg >> 3, r = nwg & 7;
    const int wgid = (xcd < r ? xcd * (q + 1) : r * (q + 1) + (xcd - r) * q) + loc;
    const int m0   = (wgid / NB) * GBM;
    const int n0   = (wgid % NB) * GBN;

    f32x4 acc[4][4] = {};

    const int byt0 = wid * 1024 + lane * 16;
    const int byt1 = byt0 + 4096;
    const int r0 = byt0 >> 6, r1 = byt1 >> 6;
    const int cs0 = (byt0 & 63) ^ (((r0 >> 1) & 3) << 4);
    const int cs1 = (byt1 & 63) ^ (((r1 >> 1) & 3) << 4);

    const unsigned short* pAh0 = Ahi  + (size_t)(m0 + r0) * K + (cs0 >> 1);
    const unsigned short* pAh1 = Ahi  + (size_t)(m0 + r1) * K + (cs1 >> 1);
    const unsigned short* pAl0 = Alo  + (size_t)(m0 + r0) * K + (cs0 >> 1);
    const unsigned short* pAl1 = Alo  + (size_t)(m0 + r1) * K + (cs1 >> 1);
    const unsigned short* pBh0 = BhiT + (size_t)(n0 + r0) * K + (cs0 >> 1);
    const unsigned short* pBh1 = BhiT + (size_t)(n0 + r1) * K + (cs1 >> 1);
    const unsigned short* pBl0 = BloT + (size_t)(n0 + r0) * K + (cs0 >> 1);
    const unsigned short* pBl1 = BloT + (size_t)(n0 + r1) * K + (cs1 >> 1);

    const int fr   = lane & 15;
    const int kbs  = ((lane >> 4) << 4) ^ (((fr >> 1) & 3) << 4);
    const int arow = wr * 64;
    const int brow = wc * 64;

    ISSUE2(pAh0, pAh1, 0);
    ISSUE2(pBh0, pBh1, 2);
    ISSUE2(pBl0, pBl1, 3);
    ISSUE2(pAl0, pAl1, 1);

    const int NT = K >> 5;
    bf16x8 ahi[4], bhi[4], blo[4], alo[4];

    for (int tt = 0; tt < NT; ++tt) {
        // ---- phase 1: hi*hi ----
        if (tt == 0) asm volatile("s_waitcnt vmcnt(4)" ::: "memory");
        else         asm volatile("s_waitcnt vmcnt(2)" ::: "memory");
        __builtin_amdgcn_s_barrier();
        #pragma unroll
        for (int i = 0; i < 4; ++i)
            ahi[i] = *(const bf16x8*)(&lds[0][(arow + i * 16 + fr) * 64 + kbs]);
        #pragma unroll
        for (int j = 0; j < 4; ++j)
            bhi[j] = *(const bf16x8*)(&lds[2][(brow + j * 16 + fr) * 64 + kbs]);
        if (tt > 0) ISSUE2(pAl0, pAl1, 1);
        __builtin_amdgcn_s_setprio(1);
        #pragma unroll
        for (int i = 0; i < 4; ++i)
            #pragma unroll
            for (int j = 0; j < 4; ++j)
                acc[i][j] = __builtin_amdgcn_mfma_f32_16x16x32_bf16(ahi[i], bhi[j], acc[i][j], 0, 0, 0);
        __builtin_amdgcn_s_setprio(0);
        // ---- phase 2: hi*lo ----
        asm volatile("s_waitcnt vmcnt(2)" ::: "memory");
        __builtin_amdgcn_s_barrier();
        #pragma unroll
        for (int j = 0; j < 4; ++j)
            blo[j] = *(const bf16x8*)(&lds[3][(brow + j * 16 + fr) * 64 + kbs]);
        if (tt < NT - 1) {
            ISSUE2(pAh0, pAh1, 0);
            ISSUE2(pBh0, pBh1, 2);
        }
        __builtin_amdgcn_s_setprio(1);
        #pragma unroll
        for (int i = 0; i < 4; ++i)
            #pragma unroll
            for (int j = 0; j < 4; ++j)
                acc[i][j] = __builtin_amdgcn_mfma_f32_16x16x32_bf16(ahi[i], blo[j], acc[i][j], 0, 0, 0);
        __builtin_amdgcn_s_setprio(0);
        // ---- phase 3: lo*hi ----
        if (tt < NT - 1) asm volatile("s_waitcnt vmcnt(4)" ::: "memory");
        else             asm volatile("s_waitcnt vmcnt(0)" ::: "memory");
        __builtin_amdgcn_s_barrier();
        #pragma unroll
        for (int i = 0; i < 4; ++i)
            alo[i] = *(const bf16x8*)(&lds[1][(arow + i * 16 + fr) * 64 + kbs]);
        if (tt < NT - 1) ISSUE2(pBl0, pBl1, 3);
        __builtin_amdgcn_s_setprio(1);
        #pragma unroll
        for (int i = 0; i < 4; ++i)
            #pragma unroll
            for (int j = 0; j < 4; ++j)
                acc[i][j] = __builtin_amdgcn_mfma_f32_16x16x32_bf16(alo[i], bhi[j], acc[i][j], 0, 0, 0);
        __builtin_amdgcn_s_setprio(0);
    }

    #pragma unroll
    for (int i = 0; i < 4; ++i) {
        #pragma unroll
        for (int j = 0; j < 4; ++j) {
            int row = m0 + wr * 64 + i * 16 + (lane >> 4) * 4;
            int col = n0 + wc * 64 + j * 16 + (lane & 15);
            float bv = (col < nbias) ? bias[col] : 0.f;
            #pragma unroll
            for (int r2 = 0; r2 < 4; ++r2)
                H[(size_t)(row + r2) * ldh + col] = acc[i][j][r2] + bv;
        }
    }
}

// ---------------- fp32 tiled GEMM (fallback path only) ----------------

#define BM 64
#define BN 64
#define BKT 16
#define TM 4
#define TN 4

__global__ __launch_bounds__(256)
void gemm_bias_kernel(const float* __restrict__ X, const float* __restrict__ W,
                      const float* __restrict__ bias, float* __restrict__ H,
                      int M, int N, int K) {
    __shared__ float As[BKT][BM];
    __shared__ float Bs[BKT][BN];

    const int t  = threadIdx.x;
    const int tx = t & 15;
    const int ty = t >> 4;
    const int m0 = blockIdx.y * BM;
    const int n0 = blockIdx.x * BN;

    float acc[TM][TN] = {};

    const int arow = t >> 2;
    const int ak0  = (t & 3) * 4;
    const int brow = t >> 4;
    const int bn0  = (t & 15) * 4;

    for (int k0 = 0; k0 < K; k0 += BKT) {
        {
            float4 v = make_float4(0.f, 0.f, 0.f, 0.f);
            int gm = m0 + arow;
            int gk = k0 + ak0;
            if (gm < M) {
                if (gk + 3 < K) {
                    v = *reinterpret_cast<const float4*>(&X[(long)gm * K + gk]);
                } else {
                    float tmp[4] = {0.f, 0.f, 0.f, 0.f};
                    for (int i = 0; i < 4; ++i)
                        if (gk + i < K) tmp[i] = X[(long)gm * K + gk + i];
                    v = make_float4(tmp[0], tmp[1], tmp[2], tmp[3]);
                }
            }
            As[ak0 + 0][arow] = v.x;
            As[ak0 + 1][arow] = v.y;
            As[ak0 + 2][arow] = v.z;
            As[ak0 + 3][arow] = v.w;
        }
        {
            float4 v = make_float4(0.f, 0.f, 0.f, 0.f);
            int gk = k0 + brow;
            int gn = n0 + bn0;
            if (gk < K) {
                if (gn + 3 < N) {
                    v = *reinterpret_cast<const float4*>(&W[(long)gk * N + gn]);
                } else {
                    float tmp[4] = {0.f, 0.f, 0.f, 0.f};
                    for (int i = 0; i < 4; ++i)
                        if (gn + i < N) tmp[i] = W[(long)gk * N + gn + i];
                    v = make_float4(tmp[0], tmp[1], tmp[2], tmp[3]);
                }
            }
            *reinterpret_cast<float4*>(&Bs[brow][bn0]) = v;
        }
        __syncthreads();

        #pragma unroll
        for (int kk = 0; kk < BKT; ++kk) {
            float a[TM], b[TN];
            *reinterpret_cast<float4*>(a) = *reinterpret_cast<const float4*>(&As[kk][ty * TM]);
            *reinterpret_cast<float4*>(b) = *reinterpret_cast<const float4*>(&Bs[kk][tx * TN]);
            #pragma unroll
            for (int i = 0; i < TM; ++i)
                #pragma unroll
                for (int j = 0; j < TN; ++j)
                    acc[i][j] += a[i] * b[j];
        }
        __syncthreads();
    }

    #pragma unroll
    for (int i = 0; i < TM; ++i) {
        int gm = m0 + ty * TM + i;
        if (gm >= M) continue;
        #pragma unroll
        for (int j = 0; j < TN; ++j) {
            int gn = n0 + tx * TN + j;
            if (gn < N) H[(long)gm * N + gn] = acc[i][j] + bias[gn];
        }
    }
}

// ---------------- aggregates ----------------

__global__ __launch_bounds__(256)
void aggregate_bf16_kernel(const float* __restrict__ H, const int* __restrict__ row_start,
                           const int* __restrict__ esrc, unsigned short* __restrict__ Xhi,
                           unsigned short* __restrict__ Xlo, int d, int ld_in, int kpad) {
    const int node = blockIdx.x;
    const int f = threadIdx.x * 4;
    if (f >= kpad) return;
    if (f >= d) {
        ushort4 z = make_ushort4(0, 0, 0, 0);
        *reinterpret_cast<ushort4*>(&Xhi[(size_t)node * kpad + f]) = z;
        *reinterpret_cast<ushort4*>(&Xlo[(size_t)node * kpad + f]) = z;
        return;
    }
    const int beg = row_start[node];
    const int end = row_start[node + 1];
    float4 acc = *reinterpret_cast<const float4*>(&H[(size_t)node * ld_in + f]);
    for (int i = beg; i < end; ++i) {
        float4 v = *reinterpret_cast<const float4*>(&H[(size_t)esrc[i] * ld_in + f]);
        acc.x += v.x; acc.y += v.y; acc.z += v.z; acc.w += v.w;
    }
    acc.x = fmaxf(acc.x, 0.f); acc.y = fmaxf(acc.y, 0.f);
    acc.z = fmaxf(acc.z, 0.f); acc.w = fmaxf(acc.w, 0.f);
    unsigned short h0 = f2bf(acc.x), h1 = f2bf(acc.y), h2 = f2bf(acc.z), h3 = f2bf(acc.w);
    unsigned short l0 = f2bf(acc.x - bf2f(h0));
    unsigned short l1 = f2bf(acc.y - bf2f(h1));
    unsigned short l2 = f2bf(acc.z - bf2f(h2));
    unsigned short l3 = f2bf(acc.w - bf2f(h3));
    *reinterpret_cast<ushort4*>(&Xhi[(size_t)node * kpad + f]) = make_ushort4(h0, h1, h2, h3);
    *reinterpret_cast<ushort4*>(&Xlo[(size_t)node * kpad + f]) = make_ushort4(l0, l1, l2, l3);
}

// fused: x3 = relu(agg(H2, d=300)) in LDS; h3 = x3 @ W3[300,20] + b3
__global__ __launch_bounds__(128)
void agg2_gemm3_kernel(const float* __restrict__ H2, const int* __restrict__ row_start,
                       const int* __restrict__ esrc, const float* __restrict__ W3,
                       const float* __restrict__ b3, float* __restrict__ h3) {
    __shared__ float x3s[304];
    __shared__ float part[6][20];
    const int node = blockIdx.x;
    const int t = threadIdx.x;
    const int beg = row_start[node];
    const int end = row_start[node + 1];
    if (t < 75) {
        const int f = t * 4;
        float4 acc = *reinterpret_cast<const float4*>(&H2[(size_t)node * LDH2 + f]);
        for (int i = beg; i < end; ++i) {
            float4 v = *reinterpret_cast<const float4*>(&H2[(size_t)esrc[i] * LDH2 + f]);
            acc.x += v.x; acc.y += v.y; acc.z += v.z; acc.w += v.w;
        }
        x3s[f + 0] = fmaxf(acc.x, 0.f);
        x3s[f + 1] = fmaxf(acc.y, 0.f);
        x3s[f + 2] = fmaxf(acc.z, 0.f);
        x3s[f + 3] = fmaxf(acc.w, 0.f);
    }
    __syncthreads();
    if (t < 120) {
        const int j = t % 20, g = t / 20;
        float s = 0.f;
        #pragma unroll 5
        for (int k = g * 50; k < g * 50 + 50; ++k)
            s += x3s[k] * W3[k * 20 + j];
        part[g][j] = s;
    }
    __syncthreads();
    if (t < 20) {
        float s = b3[t];
        #pragma unroll
        for (int g = 0; g < 6; ++g) s += part[g][t];
        h3[(size_t)node * 20 + t] = s;
    }
}

// fused: x4 = agg(h3, d=20) in LDS; h4 = x4 @ W4[20,10] + b4
__global__ __launch_bounds__(64)
void agg3_gemm4_kernel(const float* __restrict__ h3, const int* __restrict__ row_start,
                       const int* __restrict__ esrc, const float* __restrict__ W4,
                       const float* __restrict__ b4, float* __restrict__ h4) {
    __shared__ float x4s[20];
    const int node = blockIdx.x;
    const int t = threadIdx.x;
    const int beg = row_start[node];
    const int end = row_start[node + 1];
    if (t < 20) {
        float acc = h3[(size_t)node * 20 + t];
        for (int i = beg; i < end; ++i)
            acc += h3[(size_t)esrc[i] * 20 + t];
        x4s[t] = acc;
    }
    __syncthreads();
    if (t < 10) {
        float s = b4[t];
        #pragma unroll
        for (int k = 0; k < 20; ++k) s += x4s[k] * W4[k * 10 + t];
        h4[(size_t)node * 10 + t] = s;
    }
}

// small-d aggregate (d <= 64), one 64-lane wave per node
template <int ACT>
__global__ __launch_bounds__(64)
void aggregate_small_kernel(const float* __restrict__ H, const int* __restrict__ row_start,
                            const int* __restrict__ esrc, float* __restrict__ out,
                            int d, int ld_in, int ld_out) {
    const int node = blockIdx.x;
    const int f = threadIdx.x;
    if (f >= d) return;
    const int beg = row_start[node];
    const int end = row_start[node + 1];
    float acc = H[(size_t)node * ld_in + f];
    for (int i = beg; i < end; ++i)
        acc += H[(size_t)esrc[i] * ld_in + f];
    if (ACT == 1) acc = fmaxf(acc, 0.f);
    if (ACT == 2) acc = tanhf(acc);
    out[(size_t)node * ld_out + f] = acc;
}

// scalar generic aggregate (fallback path only)
template <int ACT>
__global__ __launch_bounds__(256)
void aggregate_kernel(const float* __restrict__ H, const int* __restrict__ row_start,
                      const int* __restrict__ esrc, float* __restrict__ out,
                      int d, int ld_in) {
    const int node = blockIdx.x;
    const int t = threadIdx.x;
    const int beg = row_start[node];
    const int end = row_start[node + 1];
    float acc[4] = {0.f, 0.f, 0.f, 0.f};
    #pragma unroll
    for (int j = 0; j < 4; ++j) {
        int f = t + j * 256;
        if (f < d) acc[j] = H[(size_t)node * ld_in + f];
    }
    for (int i = beg; i < end; ++i) {
        const size_t b = (size_t)esrc[i] * ld_in;
        #pragma unroll
        for (int j = 0; j < 4; ++j) {
            int f = t + j * 256;
            if (f < d) acc[j] += H[b + f];
        }
    }
    #pragma unroll
    for (int j = 0; j < 4; ++j) {
        int f = t + j * 256;
        if (f < d) {
            float v = acc[j];
            if (ACT == 1) v = fmaxf(v, 0.f);
            if (ACT == 2) v = tanhf(v);
            out[(size_t)node * d + f] = v;
        }
    }
}

// ---------------- launch ----------------

extern "C" void kernel_launch(void* const* d_in, const int* in_sizes, int n_in,
                              void* d_out, int out_size, void* d_ws, size_t ws_size,
                              hipStream_t stream) {
    const float* features = (const float*)d_in[0];
    const int*   src      = (const int*)d_in[1];
    const int*   dst      = (const int*)d_in[2];
    const float* W1 = (const float*)d_in[3];  const float* b1 = (const float*)d_in[4];
    const float* W2 = (const float*)d_in[5];  const float* b2 = (const float*)d_in[6];
    const float* W3 = (const float*)d_in[7];  const float* b3 = (const float*)d_in[8];
    const float* W4 = (const float*)d_in[9];  const float* b4 = (const float*)d_in[10];
    float* out = (float*)d_out;
    char* ws = (char*)d_ws;

    const size_t SZ_A    = (size_t)M_PAD * D_IN * 2;
    const size_t OFF_ALO = SZ_A;
    const size_t OFF_H1  = 2 * SZ_A;
    const size_t SZ_H1   = (size_t)M_PAD * LDH1 * 4;
    const size_t OFF_W1T = OFF_H1 + SZ_H1;
    const size_t SZ_W1T  = (size_t)N1_PAD * D_IN * 2;
    const size_t OFF_CSR = OFF_W1T + 2 * SZ_W1T;
    const size_t SZ_CSR  = (size_t)(N_NODES * 3 + 1 + N_EDGES) * 4;
    const size_t WS_NEED = OFF_CSR + SZ_CSR;

    const size_t SZ_X2   = (size_t)M_PAD * K2_PAD * 2;
    const size_t OFF_X2H = 0;
    const size_t OFF_X2L = SZ_X2;
    const size_t OFF_H2  = 2 * SZ_X2;
    const size_t OFF_H3  = OFF_H1 + 24000000;
    const size_t OFF_H4  = OFF_H1 + 27200000;
    const size_t OFF_W2T = OFF_H1 + 28800000;
    const size_t SZ_W2T  = (size_t)N2_PAD * K2_PAD * 2;

    const bool use_mfma = (ws_size >= WS_NEED);
    size_t csr_off = use_mfma ? OFF_CSR : (size_t)2 * N_NODES * 1000 * 4;
    int* counts    = (int*)(ws + csr_off);
    int* row_start = counts + N_NODES;
    int* cursor    = row_start + N_NODES + 1;
    int* esrc      = cursor + N_NODES;

    zero_counts_kernel<<<(N_NODES + 255) / 256, 256, 0, stream>>>(counts);
    count_kernel<<<(N_EDGES + 255) / 256, 256, 0, stream>>>(dst, counts);
    scan_kernel<<<1, 1024, 0, stream>>>(counts, row_start, cursor);
    scatter_kernel<<<(N_EDGES + 255) / 256, 256, 0, stream>>>(src, dst, cursor, esrc);

    if (use_mfma) {
        unsigned short* Ahi   = (unsigned short*)ws;
        unsigned short* Alo   = (unsigned short*)(ws + OFF_ALO);
        float*          H1    = (float*)(ws + OFF_H1);
        unsigned short* W1hiT = (unsigned short*)(ws + OFF_W1T);
        unsigned short* W1loT = (unsigned short*)(ws + OFF_W1T + SZ_W1T);
        unsigned short* X2hi  = (unsigned short*)(ws + OFF_X2H);
        unsigned short* X2lo  = (unsigned short*)(ws + OFF_X2L);
        float*          H2    = (float*)(ws + OFF_H2);
        float*          h3    = (float*)(ws + OFF_H3);
        float*          h4    = (float*)(ws + OFF_H4);
        unsigned short* W2hiT = (unsigned short*)(ws + OFF_W2T);
        unsigned short* W2loT = (unsigned short*)(ws + OFF_W2T + SZ_W2T);

        // Layer 1 (128^2, single-buffer rotation, zero-conflict swizzle)
        convA_kernel<<<(N_NODES * D_IN / 4 + 255) / 256, 256, 0, stream>>>(features, Ahi, Alo);
        convW_kernel<<<dim3(N1_PAD / 32, D_IN / 32), 256, 0, stream>>>(W1, W1hiT, W1loT, D_IN, 1000, D_IN);
        gemm_split_mfma_kernel<<<(N1_PAD / GBN) * (M_PAD / GBM), 256, 0, stream>>>(
            Ahi, Alo, W1hiT, W1loT, b1, H1, D_IN, N1_PAD / GBN, LDH1, 1000);
        aggregate_bf16_kernel<<<N_NODES, 256, 0, stream>>>(
            H1, row_start, esrc, X2hi, X2lo, 1000, LDH1, K2_PAD);

        // Layer 2 (128^2)
        convW_kernel<<<dim3(N2_PAD / 32, K2_PAD / 32), 256, 0, stream>>>(W2, W2hiT, W2loT, 1000, 300, K2_PAD);
        gemm_split_mfma_kernel<<<(N2_PAD / GBN) * (M_PAD / GBM), 256, 0, stream>>>(
            X2hi, X2lo, W2hiT, W2loT, b2, H2, K2_PAD, N2_PAD / GBN, LDH2, 300);

        // Layers 3+4 fused: agg2+gemm3, agg3+gemm4, agg4+tanh
        agg2_gemm3_kernel<<<N_NODES, 128, 0, stream>>>(H2, row_start, esrc, W3, b3, h3);
        agg3_gemm4_kernel<<<N_NODES, 64, 0, stream>>>(h3, row_start, esrc, W4, b4, h4);
        aggregate_small_kernel<2><<<N_NODES, 64, 0, stream>>>(h4, row_start, esrc, out, 10, 10, 10);
    } else {
        const size_t BUF = (size_t)N_NODES * 1000 * 4;
        float* bufA = (float*)ws;
        float* bufB = (float*)(ws + BUF);

        dim3 g1((1000 + BN - 1) / BN, (N_NODES + BM - 1) / BM);
        gemm_bias_kernel<<<g1, 256, 0, stream>>>(features, W1, b1, bufA, N_NODES, 1000, D_IN);
        aggregate_kernel<1><<<N_NODES, 256, 0, stream>>>(bufA, row_start, esrc, bufB, 1000, 1000);

        dim3 g2((300 + BN - 1) / BN, (N_NODES + BM - 1) / BM);
        gemm_bias_kernel<<<g2, 256, 0, stream>>>(bufB, W2, b2, bufA, N_NODES, 300, 1000);
        aggregate_kernel<1><<<N_NODES, 256, 0, stream>>>(bufA, row_start, esrc, bufB, 300, 300);

        dim3 g3((20 + BN - 1) / BN, (N_NODES + BM - 1) / BM);
        gemm_bias_kernel<<<g3, 256, 0, stream>>>(bufB, W3, b3, bufA, N_NODES, 20, 300);
        aggregate_kernel<0><<<N_NODES, 256, 0, stream>>>(bufA, row_start, esrc, bufB, 20, 20);

        dim3 g4((10 + BN - 1) / BN, (N_NODES + BM - 1) / BM);
        gemm_bias_kernel<<<g4, 256, 0, stream>>>(bufB, W4, b4, bufA, N_NODES, 10, 20);
        aggregate_kernel<2><<<N_NODES, 256, 0, stream>>>(bufA, row_start, esrc, out, 10, 10);
    }
}